// Round 17
// baseline (467.593 us; speedup 1.0000x reference)
//
#include <hip/hip_runtime.h>
#include <hip/hip_cooperative_groups.h>
#include <hip/hip_bf16.h>
#include <cstdint>
#include <math.h>

namespace cg = cooperative_groups;

#define F_IN 512
#define HID  16
#define NCLS 40
#define OUT_STRIDE 20
#define TB   256     // nodes per dst-bucket (bucket = dst >> 8)
#define PARTB 256    // partition blocks (chunk/NB ~= 32-edge runs)
#define CAP  16384   // padded bin capacity per bucket (mean 8192, sigma ~90)

typedef __attribute__((ext_vector_type(8))) short short8;
typedef __attribute__((ext_vector_type(4))) float f32x4;

__device__ inline unsigned short f2bf(float f) {      // RNE f32 -> bf16
    unsigned u = __float_as_uint(f);
    u += 0x7fff + ((u >> 16) & 1);
    return (unsigned short)(u >> 16);
}
__device__ inline float bf2f(unsigned v) {            // low 16 bits -> f32
    return __uint_as_float(v << 16);
}

// ================= single fused cooperative kernel =================
// Phase A: part (blocks<PARTB) || gemm 64-row tile queue (all waves)
// Phase B: sortb + in-place h1 scale (blocks<NB)
// Phase C: agg (grid-stride waves)
// Phase D: out (grid-stride waves)
__global__ __launch_bounds__(256) void k_fused(
    const float* __restrict__ x, const float* __restrict__ W1,
    unsigned short* __restrict__ h1b,
    const int* __restrict__ src, const int* __restrict__ dst,
    int* __restrict__ gcnt, unsigned* __restrict__ bin,
    int* __restrict__ csr, int2* __restrict__ rng, float* __restrict__ dinv,
    unsigned short* __restrict__ zb, const float* __restrict__ b1,
    const float* __restrict__ W2, const float* __restrict__ b2,
    float* __restrict__ out,
    int E, int N, int NB, int chunk, int GT, int* tilec, int nOut)
{
    cg::grid_group grid = cg::this_grid();
    __shared__ uint4 bl[16 * 64];          // 16 KB union: part h/pos | W frags | sort arrays
    int t = threadIdx.x, blk = blockIdx.x;
    int lane = t & 63;

    // ---------- Phase A1: partition ----------
    if (blk < PARTB) {
        int* h   = (int*)bl;      // 512 ints
        int* pos = h + 512;       // 512 ints
        for (int b = t; b < NB; b += 256) h[b] = 0;
        __syncthreads();
        int e0 = blk * chunk, e1 = min(E, e0 + chunk);
        int nvec = (e1 - e0) >> 2;
        const int4* d4 = (const int4*)(dst + e0);
        const int4* s4 = (const int4*)(src + e0);
        for (int i = t; i < nvec; i += 256) {
            int4 d = d4[i];
            atomicAdd(&h[d.x >> 8], 1);
            atomicAdd(&h[d.y >> 8], 1);
            atomicAdd(&h[d.z >> 8], 1);
            atomicAdd(&h[d.w >> 8], 1);
        }
        for (int e = e0 + nvec * 4 + t; e < e1; e += 256)
            atomicAdd(&h[dst[e] >> 8], 1);
        __syncthreads();
        for (int b = t; b < NB; b += 256) {
            int c = h[b];
            int rb = c ? atomicAdd(&gcnt[b], c) : 0;
            pos[b] = b * CAP + rb;
        }
        __syncthreads();
        for (int i = t; i < nvec; i += 256) {   // L2-hot from pass 1
            int4 d = d4[i];
            int4 s = s4[i];
            int p;
            p = atomicAdd(&pos[d.x >> 8], 1); bin[p] = ((unsigned)s.x << 8) | (unsigned)(d.x & (TB - 1));
            p = atomicAdd(&pos[d.y >> 8], 1); bin[p] = ((unsigned)s.y << 8) | (unsigned)(d.y & (TB - 1));
            p = atomicAdd(&pos[d.z >> 8], 1); bin[p] = ((unsigned)s.z << 8) | (unsigned)(d.z & (TB - 1));
            p = atomicAdd(&pos[d.w >> 8], 1); bin[p] = ((unsigned)s.w << 8) | (unsigned)(d.w & (TB - 1));
        }
        for (int e = e0 + nvec * 4 + t; e < e1; e += 256) {
            int d = dst[e], s = src[e];
            int p = atomicAdd(&pos[d >> 8], 1);
            bin[p] = ((unsigned)s << 8) | (unsigned)(d & (TB - 1));
        }
        __syncthreads();   // bl free for W-pack
    }

    // ---------- Phase A2: pack W1 frags to LDS, drain gemm tile queue ----------
    for (int f = t; f < 16 * 64; f += 256) {
        int kstep = f >> 6, ln = f & 63;
        int col = ln & 15, k0 = kstep * 32 + (ln >> 4) * 8;
        unsigned up[4];
#pragma unroll
        for (int i = 0; i < 4; i++) {
            float a = W1[(k0 + 2 * i) * HID + col];
            float b = W1[(k0 + 2 * i + 1) * HID + col];
            up[i] = (unsigned)f2bf(a) | ((unsigned)f2bf(b) << 16);
        }
        bl[f] = make_uint4(up[0], up[1], up[2], up[3]);
    }
    __syncthreads();

    {
        int arow = lane & 15, kgrp = lane >> 4;
        for (;;) {
            int tl;
            if (lane == 0) tl = atomicAdd(tilec, 1);
            tl = __shfl(tl, 0);
            if (tl >= GT) break;
            int rows0 = tl * 64;

            const float* xr[4];
#pragma unroll
            for (int rt = 0; rt < 4; rt++) {
                int r = rows0 + rt * 16 + arow;
                if (r >= N) r = N - 1;
                xr[rt] = x + (size_t)r * F_IN + kgrp * 8;
            }
            f32x4 acc[4];
#pragma unroll
            for (int rt = 0; rt < 4; rt++) acc[rt] = (f32x4){0.f, 0.f, 0.f, 0.f};

#pragma unroll 4
            for (int kstep = 0; kstep < 16; kstep++) {
                uint4 braw = bl[kstep * 64 + lane];
                short8 b;
                *(uint4*)&b = braw;
#pragma unroll
                for (int rt = 0; rt < 4; rt++) {
                    f32x4 lo = __builtin_nontemporal_load((const f32x4*)(xr[rt] + kstep * 32));
                    f32x4 hi = __builtin_nontemporal_load((const f32x4*)(xr[rt] + kstep * 32 + 4));
                    __hip_bfloat162 c0 = __float22bfloat162_rn(make_float2(lo[0], lo[1]));
                    __hip_bfloat162 c1 = __float22bfloat162_rn(make_float2(lo[2], lo[3]));
                    __hip_bfloat162 c2 = __float22bfloat162_rn(make_float2(hi[0], hi[1]));
                    __hip_bfloat162 c3 = __float22bfloat162_rn(make_float2(hi[2], hi[3]));
                    uint4 araw;
                    __builtin_memcpy(&araw.x, &c0, 4);
                    __builtin_memcpy(&araw.y, &c1, 4);
                    __builtin_memcpy(&araw.z, &c2, 4);
                    __builtin_memcpy(&araw.w, &c3, 4);
                    short8 a;
                    *(uint4*)&a = araw;
                    acc[rt] = __builtin_amdgcn_mfma_f32_16x16x32_bf16(a, b, acc[rt], 0, 0, 0);
                }
            }
            int col = lane & 15, rbase = (lane >> 4) * 4;
#pragma unroll
            for (int rt = 0; rt < 4; rt++) {
#pragma unroll
                for (int r = 0; r < 4; r++) {
                    int row = rows0 + rt * 16 + rbase + r;
                    if (row < N)
                        h1b[(size_t)row * HID + col] = f2bf(acc[rt][r]);   // unscaled
                }
            }
        }
    }
    grid.sync();

    // ---------- Phase B: sortb + in-place h1 scale ----------
    if (blk < NB) {
        int* cnt  = (int*)bl;        // 256
        int* incl = cnt + 256;       // 256
        int* pos  = incl + 256;      // 256
        cnt[t] = 0;
        __syncthreads();
        int j0 = blk * CAP, count = gcnt[blk];
        for (int j = t; j < count; j += 256)
            atomicAdd(&cnt[bin[j0 + j] & (TB - 1)], 1);
        __syncthreads();
        incl[t] = cnt[t];
        __syncthreads();
        for (int off = 1; off < TB; off <<= 1) {
            int v = (t >= off) ? incl[t - off] : 0;
            __syncthreads();
            incl[t] += v;
            __syncthreads();
        }
        int ex = incl[t] - cnt[t];
        pos[t] = ex;
        int node = blk * TB + t;
        float dv = rsqrtf((float)cnt[t] + 1.0f);      // +1 self loop
        if (node < N) {
            rng[node] = make_int2(j0 + ex, j0 + ex + cnt[t]);
            dinv[node] = dv;
            uint4* p = (uint4*)(h1b + (size_t)node * HID);
            uint4 lo = p[0], hi = p[1];
            unsigned w[8] = {lo.x, lo.y, lo.z, lo.w, hi.x, hi.y, hi.z, hi.w};
#pragma unroll
            for (int i = 0; i < 8; i++) {
                float a = bf2f(w[i] & 0xffff) * dv;
                float c = bf2f(w[i] >> 16) * dv;
                w[i] = (unsigned)f2bf(a) | ((unsigned)f2bf(c) << 16);
            }
            p[0] = make_uint4(w[0], w[1], w[2], w[3]);
            p[1] = make_uint4(w[4], w[5], w[6], w[7]);
        }
        __syncthreads();
        for (int j = t; j < count; j += 256) {
            unsigned v = bin[j0 + j];
            int pp = atomicAdd(&pos[v & (TB - 1)], 1);
            csr[j0 + pp] = (int)(v >> 8);
        }
    }
    grid.sync();

    // ---------- Phase C: agg (grid-stride waves, 16 subgroups x 4 lanes) ----------
    {
        const uint2* h1u2 = (const uint2*)h1b;
        uint2* zu2 = (uint2*)zb;
        int wave0 = (blk * 256 + t) >> 6;
        int nwaves = gridDim.x * 4;
        int c2 = lane & 3;
        int sub = lane >> 2;
        float bl0 = b1[4 * c2 + 0], bl1 = b1[4 * c2 + 1];
        float bl2 = b1[4 * c2 + 2], bl3 = b1[4 * c2 + 3];
        for (int node = wave0; node < N; node += nwaves) {
            int2 r = rng[node];
            int s0 = r.x, s1 = r.y;
            uint2 us = h1u2[(size_t)node * 4 + c2];   // self loop, issued early
            float s[4] = {0.f, 0.f, 0.f, 0.f};
            int j = s0 + sub;
            int nxt = (j < s1) ? __builtin_nontemporal_load(&csr[j]) : 0;
            for (; j < s1; j += 16) {
                int cur = nxt;
                int jn = j + 16;
                if (jn < s1) nxt = __builtin_nontemporal_load(&csr[jn]);
                uint2 u = h1u2[(size_t)cur * 4 + c2];
                s[0] += bf2f(u.x & 0xffff); s[1] += bf2f(u.x >> 16);
                s[2] += bf2f(u.y & 0xffff); s[3] += bf2f(u.y >> 16);
            }
#pragma unroll
            for (int m = 4; m < 64; m <<= 1) {
                s[0] += __shfl_xor(s[0], m); s[1] += __shfl_xor(s[1], m);
                s[2] += __shfl_xor(s[2], m); s[3] += __shfl_xor(s[3], m);
            }
            s[0] += bf2f(us.x & 0xffff); s[1] += bf2f(us.x >> 16);
            s[2] += bf2f(us.y & 0xffff); s[3] += bf2f(us.y >> 16);
            float dv = dinv[node];
            float p0 = dv * s[0] + bl0;
            float p1 = dv * s[1] + bl1;
            float p2 = dv * s[2] + bl2;
            float p3 = dv * s[3] + bl3;
            if (lane < 4) {
                uint2 o;
                o.x = (unsigned)f2bf(fmaxf(p0, 0.f) * dv) | ((unsigned)f2bf(fmaxf(p1, 0.f) * dv) << 16);
                o.y = (unsigned)f2bf(fmaxf(p2, 0.f) * dv) | ((unsigned)f2bf(fmaxf(p3, 0.f) * dv) << 16);
                zu2[(size_t)node * 4 + c2] = o;
            }
        }
    }
    grid.sync();

    // ---------- Phase D: out (grid-stride waves) ----------
    {
        int wave0 = (blk * 256 + t) >> 6;
        int nwaves = gridDim.x * 4;
        int c = lane & 15, sub = lane >> 4;
        for (int wv = wave0; wv < nOut; wv += nwaves) {
            int node = wv * OUT_STRIDE;
            int2 r = rng[node];
            int s0 = r.x, s1 = r.y;
            float sum = 0.f;
            for (int j = s0 + sub; j < s1; j += 4)
                sum += bf2f(zb[(size_t)__builtin_nontemporal_load(&csr[j]) * HID + c]);
            sum += __shfl_xor(sum, 16);
            sum += __shfl_xor(sum, 32);
            sum += bf2f(zb[(size_t)node * HID + c]);  // self loop
            float a = dinv[node] * sum;

            int jj = lane < NCLS ? lane : 0;
            float v = 0.f;
#pragma unroll
            for (int cc = 0; cc < 16; cc++) {
                float ac = __shfl(a, cc);
                v = fmaf(ac, W2[cc * NCLS + jj], v);
            }
            v += b2[jj];

            float vm = lane < NCLS ? v : -INFINITY;
            for (int off = 1; off < 64; off <<= 1) vm = fmaxf(vm, __shfl_xor(vm, off));
            float ex = lane < NCLS ? expf(v - vm) : 0.f;
            float se = ex;
            for (int off = 1; off < 64; off <<= 1) se += __shfl_xor(se, off);
            float ls = logf(se);
            if (lane < NCLS) out[(size_t)wv * NCLS + lane] = v - vm - ls;
        }
    }
}

// ---------------- host launcher ----------------
extern "C" void kernel_launch(void* const* d_in, const int* in_sizes, int n_in,
                              void* d_out, int out_size, void* d_ws, size_t ws_size,
                              hipStream_t stream) {
    const int E = in_sizes[0] / 2;
    const int N = in_sizes[1] / F_IN;
    const int nOut = (N + OUT_STRIDE - 1) / OUT_STRIDE;
    const int NB = (N + TB - 1) / TB;                        // 391
    const int chunk = ((E + PARTB - 1) / PARTB + 3) & ~3;    // %4==0
    const int GT = (N + 63) / 64;                            // 64-row gemm tiles

    const float* x  = (const float*)d_in[1];
    const float* W1 = (const float*)d_in[2];
    const float* b1 = (const float*)d_in[3];
    const float* W2 = (const float*)d_in[4];
    const float* b2 = (const float*)d_in[5];
    const int* src = (const int*)d_in[0];
    const int* dst = src + E;
    float* out = (float*)d_out;

    uint8_t* w = (uint8_t*)d_ws;
    size_t off = 0;
    auto carve = [&](size_t bytes) {
        void* p = w + off;
        off += (bytes + 15) & ~(size_t)15;
        return p;
    };
    float*          dinv  = (float*)carve((size_t)N * 4);
    int*            gcnt  = (int*)carve((size_t)(NB + 4) * 4);   // gcnt[NB] + tilec
    unsigned*       bin   = (unsigned*)carve((size_t)NB * CAP * 4);
    int*            csr   = (int*)carve((size_t)NB * CAP * 4);
    int2*           rng   = (int2*)carve((size_t)N * 8);
    unsigned short* h1b   = (unsigned short*)carve((size_t)N * HID * 2);
    unsigned short* zb    = (unsigned short*)carve((size_t)N * HID * 2);
    int*            tilec = gcnt + NB;
    (void)ws_size; (void)n_in; (void)out_size;

    // grid sized for guaranteed co-residency
    int maxb = 0;
    if (hipOccupancyMaxActiveBlocksPerMultiprocessor(&maxb, k_fused, 256, 0)
        != hipSuccess || maxb < 2) maxb = 2;
    int grid = maxb * 256;
    if (grid > 1024) grid = 1024;
    if (grid < 512)  grid = 512;     // >= NB and >= PARTB guaranteed

    (void)hipMemsetAsync(gcnt, 0, (size_t)(NB + 4) * 4, stream);

    int Ee = E, Nn = N, NBv = NB, chv = chunk, GTv = GT, nOv = nOut;
    void* ka[] = {(void*)&x, (void*)&W1, (void*)&h1b, (void*)&src, (void*)&dst,
                  (void*)&gcnt, (void*)&bin, (void*)&csr, (void*)&rng, (void*)&dinv,
                  (void*)&zb, (void*)&b1, (void*)&W2, (void*)&b2, (void*)&out,
                  (void*)&Ee, (void*)&Nn, (void*)&NBv, (void*)&chv, (void*)&GTv,
                  (void*)&tilec, (void*)&nOv};
    (void)hipLaunchCooperativeKernel((void*)k_fused, dim3(grid), dim3(256),
                                     ka, 0, stream);
}

// Round 18
// 192.312 us; speedup vs baseline: 2.4314x; 2.4314x over previous
//
#include <hip/hip_runtime.h>
#include <hip/hip_bf16.h>
#include <cstdint>
#include <math.h>

#define F_IN 512
#define HID  16
#define NCLS 40
#define OUT_STRIDE 20
#define TB   256     // nodes per dst-bucket (bucket = dst >> 8)
#define PARTB 256    // partition blocks
#define CAP  16384   // padded bin capacity per bucket (mean 8192, sigma ~90)

typedef __attribute__((ext_vector_type(8))) short short8;
typedef __attribute__((ext_vector_type(4))) float f32x4;

__device__ inline unsigned short f2bf(float f) {      // RNE f32 -> bf16
    unsigned u = __float_as_uint(f);
    u += 0x7fff + ((u >> 16) & 1);
    return (unsigned short)(u >> 16);
}
__device__ inline float bf2f(unsigned v) {            // low 16 bits -> f32
    return __uint_as_float(v << 16);
}

// ---------- Mega1: part-blocks partition, then ALL blocks drain gemm queue ----
// gemm: h1b[i][c] = bf16(x[i] . W1[:,c])   (UNSCALED; dinv applied in sortb2)
// tile queue (64 rows per pop) load-balances gemm across all 647 blocks.
__global__ __launch_bounds__(256) void k_mega1(const float* __restrict__ x,
                                               const float* __restrict__ W1,
                                               unsigned short* __restrict__ h1b,
                                               const int* __restrict__ src,
                                               const int* __restrict__ dst,
                                               int* __restrict__ gcnt,
                                               unsigned* __restrict__ bin,
                                               int* __restrict__ tilec,
                                               int E, int NB, int chunk,
                                               int n, int GT, int GB) {
    __shared__ uint4 bl[16 * 64];          // 16 KB union: part h/pos | W frags
    int t = threadIdx.x;
    int lane = t & 63;

    if ((int)blockIdx.x >= GB) {
        // ---- PART branch first (blocks GB..GB+PARTB-1) ----
        int blk = blockIdx.x - GB;
        int* h = (int*)bl;            // 512 ints
        int* pos = h + 512;           // 512 ints
        for (int b = t; b < NB; b += 256) h[b] = 0;
        __syncthreads();
        int e0 = blk * chunk, e1 = min(E, e0 + chunk);
        int nvec = (e1 - e0) >> 2;
        const int4* d4 = (const int4*)(dst + e0);
        const int4* s4 = (const int4*)(src + e0);
        for (int i = t; i < nvec; i += 256) {
            int4 d = d4[i];                   // cacheable: pass 2 hits L2
            atomicAdd(&h[d.x >> 8], 1);
            atomicAdd(&h[d.y >> 8], 1);
            atomicAdd(&h[d.z >> 8], 1);
            atomicAdd(&h[d.w >> 8], 1);
        }
        for (int e = e0 + nvec * 4 + t; e < e1; e += 256)
            atomicAdd(&h[dst[e] >> 8], 1);
        __syncthreads();
        for (int b = t; b < NB; b += 256) {
            int c = h[b];
            int rb = c ? atomicAdd(&gcnt[b], c) : 0;
            pos[b] = b * CAP + rb;
        }
        __syncthreads();
        for (int i = t; i < nvec; i += 256) { // chunk is L2-hot from pass 1
            int4 d = d4[i];
            int4 s = s4[i];
            int p;
            p = atomicAdd(&pos[d.x >> 8], 1); bin[p] = ((unsigned)s.x << 8) | (unsigned)(d.x & (TB - 1));
            p = atomicAdd(&pos[d.y >> 8], 1); bin[p] = ((unsigned)s.y << 8) | (unsigned)(d.y & (TB - 1));
            p = atomicAdd(&pos[d.z >> 8], 1); bin[p] = ((unsigned)s.z << 8) | (unsigned)(d.z & (TB - 1));
            p = atomicAdd(&pos[d.w >> 8], 1); bin[p] = ((unsigned)s.w << 8) | (unsigned)(d.w & (TB - 1));
        }
        for (int e = e0 + nvec * 4 + t; e < e1; e += 256) {
            int d = dst[e], s = src[e];
            int p = atomicAdd(&pos[d >> 8], 1);
            bin[p] = ((unsigned)s << 8) | (unsigned)(d & (TB - 1));
        }
        __syncthreads();   // bl free for W-pack
    }

    // ---- GEMM: pack W1 frags to LDS, then drain the 64-row tile queue ----
    for (int f = t; f < 16 * 64; f += 256) {
        int kstep = f >> 6, ln = f & 63;
        int col = ln & 15, k0 = kstep * 32 + (ln >> 4) * 8;
        unsigned up[4];
#pragma unroll
        for (int i = 0; i < 4; i++) {
            float a = W1[(k0 + 2 * i) * HID + col];
            float b = W1[(k0 + 2 * i + 1) * HID + col];
            up[i] = (unsigned)f2bf(a) | ((unsigned)f2bf(b) << 16);
        }
        bl[f] = make_uint4(up[0], up[1], up[2], up[3]);
    }
    __syncthreads();

    int arow = lane & 15, kgrp = lane >> 4;
    for (;;) {
        int tl;
        if (lane == 0) tl = atomicAdd(tilec, 1);
        tl = __shfl(tl, 0);
        if (tl >= GT) break;
        int rows0 = tl * 64;

        const float* xr[4];
#pragma unroll
        for (int rt = 0; rt < 4; rt++) {
            int r = rows0 + rt * 16 + arow;
            if (r >= n) r = n - 1;                 // clamp loads; stores guarded
            xr[rt] = x + (size_t)r * F_IN + kgrp * 8;
        }
        f32x4 acc[4];
#pragma unroll
        for (int rt = 0; rt < 4; rt++) acc[rt] = (f32x4){0.f, 0.f, 0.f, 0.f};

#pragma unroll 4
        for (int kstep = 0; kstep < 16; kstep++) {
            uint4 braw = bl[kstep * 64 + lane];
            short8 b;
            *(uint4*)&b = braw;
#pragma unroll
            for (int rt = 0; rt < 4; rt++) {
                f32x4 lo = __builtin_nontemporal_load((const f32x4*)(xr[rt] + kstep * 32));
                f32x4 hi = __builtin_nontemporal_load((const f32x4*)(xr[rt] + kstep * 32 + 4));
                __hip_bfloat162 c0 = __float22bfloat162_rn(make_float2(lo[0], lo[1]));
                __hip_bfloat162 c1 = __float22bfloat162_rn(make_float2(lo[2], lo[3]));
                __hip_bfloat162 c2 = __float22bfloat162_rn(make_float2(hi[0], hi[1]));
                __hip_bfloat162 c3 = __float22bfloat162_rn(make_float2(hi[2], hi[3]));
                uint4 araw;
                __builtin_memcpy(&araw.x, &c0, 4);
                __builtin_memcpy(&araw.y, &c1, 4);
                __builtin_memcpy(&araw.z, &c2, 4);
                __builtin_memcpy(&araw.w, &c3, 4);
                short8 a;
                *(uint4*)&a = araw;
                acc[rt] = __builtin_amdgcn_mfma_f32_16x16x32_bf16(a, b, acc[rt], 0, 0, 0);
            }
        }
        int col = lane & 15, rbase = (lane >> 4) * 4;
#pragma unroll
        for (int rt = 0; rt < 4; rt++) {
#pragma unroll
            for (int r = 0; r < 4; r++) {
                int row = rows0 + rt * 16 + rbase + r;
                if (row < n)
                    h1b[(size_t)row * HID + col] = f2bf(acc[rt][r]);   // unscaled
            }
        }
    }
}

// ---------- Sortb2: counting sort -> CSR + rng + dinv, AND scale h1 in place ----
__global__ __launch_bounds__(256) void k_sortb2(const unsigned* __restrict__ bin,
                                                const int* __restrict__ gcnt,
                                                int* __restrict__ csr,
                                                int2* __restrict__ rng,
                                                float* __restrict__ dinv,
                                                unsigned short* __restrict__ h1b,
                                                int N) {
    __shared__ int cnt[TB], incl[TB], pos[TB];
    int t = threadIdx.x, b = blockIdx.x;
    cnt[t] = 0;
    __syncthreads();
    int j0 = b * CAP, count = gcnt[b];
    for (int j = t; j < count; j += 256)
        atomicAdd(&cnt[bin[j0 + j] & (TB - 1)], 1);
    __syncthreads();
    incl[t] = cnt[t];
    __syncthreads();
    for (int off = 1; off < TB; off <<= 1) {
        int v = (t >= off) ? incl[t - off] : 0;
        __syncthreads();
        incl[t] += v;
        __syncthreads();
    }
    int ex = incl[t] - cnt[t];
    pos[t] = ex;
    int node = b * TB + t;
    float dv = rsqrtf((float)cnt[t] + 1.0f);      // +1 self loop
    if (node < N) {
        rng[node] = make_int2(j0 + ex, j0 + ex + cnt[t]);
        dinv[node] = dv;
        uint4* p = (uint4*)(h1b + (size_t)node * HID);
        uint4 lo = p[0], hi = p[1];
        unsigned w[8] = {lo.x, lo.y, lo.z, lo.w, hi.x, hi.y, hi.z, hi.w};
#pragma unroll
        for (int i = 0; i < 8; i++) {
            float a = bf2f(w[i] & 0xffff) * dv;
            float c = bf2f(w[i] >> 16) * dv;
            w[i] = (unsigned)f2bf(a) | ((unsigned)f2bf(c) << 16);
        }
        p[0] = make_uint4(w[0], w[1], w[2], w[3]);
        p[1] = make_uint4(w[4], w[5], w[6], w[7]);
    }
    __syncthreads();
    for (int j = t; j < count; j += 256) {
        unsigned v = bin[j0 + j];
        int pp = atomicAdd(&pos[v & (TB - 1)], 1);
        csr[j0 + pp] = (int)(v >> 8);
    }
}

// ---------- Agg: grid-stride wave-per-node, 16x4; nt csr stream ----------
__global__ __launch_bounds__(256) void k_agg(const uint2* __restrict__ h1u2,
                                             const int* __restrict__ csr,
                                             const int2* __restrict__ rng,
                                             const float* __restrict__ dinv,
                                             const float* __restrict__ b1,
                                             uint2* __restrict__ zu2, int n) {
    int lane = threadIdx.x & 63;
    int wave0 = (blockIdx.x * blockDim.x + threadIdx.x) >> 6;
    int nwaves = (gridDim.x * blockDim.x) >> 6;
    int c2 = lane & 3;        // uint2 index: cols 4c2 .. 4c2+3
    int sub = lane >> 2;      // 16 subgroups -> 16 edges in flight
    float bl0 = b1[4 * c2 + 0], bl1 = b1[4 * c2 + 1];
    float bl2 = b1[4 * c2 + 2], bl3 = b1[4 * c2 + 3];
    for (int node = wave0; node < n; node += nwaves) {
        int2 r = rng[node];
        int s0 = r.x, s1 = r.y;
        uint2 us = h1u2[(size_t)node * 4 + c2];   // self loop, issued early
        float s[4] = {0.f, 0.f, 0.f, 0.f};
        int j = s0 + sub;
        int nxt = (j < s1) ? __builtin_nontemporal_load(&csr[j]) : 0;
        for (; j < s1; j += 16) {
            int cur = nxt;
            int jn = j + 16;
            if (jn < s1) nxt = __builtin_nontemporal_load(&csr[jn]);
            uint2 u = h1u2[(size_t)cur * 4 + c2];
            s[0] += bf2f(u.x & 0xffff); s[1] += bf2f(u.x >> 16);
            s[2] += bf2f(u.y & 0xffff); s[3] += bf2f(u.y >> 16);
        }
#pragma unroll
        for (int m = 4; m < 64; m <<= 1) {
            s[0] += __shfl_xor(s[0], m); s[1] += __shfl_xor(s[1], m);
            s[2] += __shfl_xor(s[2], m); s[3] += __shfl_xor(s[3], m);
        }
        s[0] += bf2f(us.x & 0xffff); s[1] += bf2f(us.x >> 16);
        s[2] += bf2f(us.y & 0xffff); s[3] += bf2f(us.y >> 16);
        float dv = dinv[node];
        float p0 = dv * s[0] + bl0;
        float p1 = dv * s[1] + bl1;
        float p2 = dv * s[2] + bl2;
        float p3 = dv * s[3] + bl3;
        if (lane < 4) {
            uint2 o;
            o.x = (unsigned)f2bf(fmaxf(p0, 0.f) * dv) | ((unsigned)f2bf(fmaxf(p1, 0.f) * dv) << 16);
            o.y = (unsigned)f2bf(fmaxf(p2, 0.f) * dv) | ((unsigned)f2bf(fmaxf(p3, 0.f) * dv) << 16);
            zu2[(size_t)node * 4 + c2] = o;
        }
    }
}

// ---------- Out: layer-2 gather (rows %20 only) + matvec + log_softmax ----------
__global__ void k_out(const unsigned short* __restrict__ zb,
                      const int* __restrict__ csr, const int2* __restrict__ rng,
                      const float* __restrict__ dinv, const float* __restrict__ W2,
                      const float* __restrict__ b2, float* __restrict__ out, int nOut) {
    int lane = threadIdx.x & 63;
    int wv = (blockIdx.x * blockDim.x + threadIdx.x) >> 6;  // one wave per out row
    if (wv >= nOut) return;
    int node = wv * OUT_STRIDE;
    int c = lane & 15, sub = lane >> 4;
    int2 r = rng[node];
    int s0 = r.x, s1 = r.y;
    float sum = 0.f;
    for (int j = s0 + sub; j < s1; j += 4)
        sum += bf2f(zb[(size_t)__builtin_nontemporal_load(&csr[j]) * HID + c]);
    sum += __shfl_xor(sum, 16);
    sum += __shfl_xor(sum, 32);
    sum += bf2f(zb[(size_t)node * HID + c]);  // self loop
    float a = dinv[node] * sum;

    int jj = lane < NCLS ? lane : 0;
    float v = 0.f;
#pragma unroll
    for (int cc = 0; cc < 16; cc++) {
        float ac = __shfl(a, cc);  // lane cc holds column cc
        v = fmaf(ac, W2[cc * NCLS + jj], v);
    }
    v += b2[jj];

    float vm = lane < NCLS ? v : -INFINITY;
    for (int off = 1; off < 64; off <<= 1) vm = fmaxf(vm, __shfl_xor(vm, off));
    float ex = lane < NCLS ? expf(v - vm) : 0.f;
    float se = ex;
    for (int off = 1; off < 64; off <<= 1) se += __shfl_xor(se, off);
    float ls = logf(se);
    if (lane < NCLS) out[(size_t)wv * NCLS + lane] = v - vm - ls;
}

// ---------------- host launcher ----------------
extern "C" void kernel_launch(void* const* d_in, const int* in_sizes, int n_in,
                              void* d_out, int out_size, void* d_ws, size_t ws_size,
                              hipStream_t stream) {
    const int E = in_sizes[0] / 2;
    const int N = in_sizes[1] / F_IN;
    const int nOut = (N + OUT_STRIDE - 1) / OUT_STRIDE;
    const int NB = (N + TB - 1) / TB;                        // 391
    const int chunk = ((E + PARTB - 1) / PARTB + 3) & ~3;    // %4==0
    const int GT = (N + 63) / 64;                            // 64-row gemm tiles
    const int GB = 391;                                      // dedicated gemm blocks

    const int* src = (const int*)d_in[0];
    const int* dst = src + E;
    const float* x  = (const float*)d_in[1];
    const float* W1 = (const float*)d_in[2];
    const float* b1 = (const float*)d_in[3];
    const float* W2 = (const float*)d_in[4];
    const float* b2 = (const float*)d_in[5];
    float* out = (float*)d_out;

    uint8_t* w = (uint8_t*)d_ws;
    size_t off = 0;
    auto carve = [&](size_t bytes) {
        void* p = w + off;
        off += (bytes + 15) & ~(size_t)15;
        return p;
    };
    float*          dinv  = (float*)carve((size_t)N * 4);
    int*            gcnt  = (int*)carve((size_t)(NB + 4) * 4);   // gcnt[NB] + tilec
    unsigned*       bin   = (unsigned*)carve((size_t)NB * CAP * 4);
    int*            csr   = (int*)carve((size_t)NB * CAP * 4);
    int2*           rng   = (int2*)carve((size_t)N * 8);
    unsigned short* h1b   = (unsigned short*)carve((size_t)N * HID * 2);
    unsigned short* zb    = (unsigned short*)carve((size_t)N * HID * 2);
    int*            tilec = gcnt + NB;
    (void)ws_size; (void)n_in; (void)out_size;

    (void)hipMemsetAsync(gcnt, 0, (size_t)(NB + 4) * 4, stream);
    k_mega1<<<GB + PARTB, 256, 0, stream>>>(x, W1, h1b, src, dst, gcnt, bin,
                                            tilec, E, NB, chunk, N, GT, GB);
    k_sortb2<<<NB, TB, 0, stream>>>(bin, gcnt, csr, rng, dinv, h1b, N);
    k_agg  <<<2048, 256, 0, stream>>>((const uint2*)h1b, csr, rng, dinv, b1, (uint2*)zb, N);
    k_out  <<<(nOut * 64 + 255) / 256, 256, 0, stream>>>(zb, csr, rng, dinv, W2, b2, out, nOut);
}

// Round 19
// 171.806 us; speedup vs baseline: 2.7216x; 1.1194x over previous
//
#include <hip/hip_runtime.h>
#include <hip/hip_bf16.h>
#include <cstdint>
#include <math.h>

#define F_IN 512
#define HID  16
#define NCLS 40
#define OUT_STRIDE 20
#define TB   256     // nodes per dst-bucket (bucket = dst >> 8)
#define NBA  256     // partition-phase blocks
#define CAP  16384   // padded bin capacity per bucket (mean 8192, sigma ~90)

typedef __attribute__((ext_vector_type(8))) short short8;
typedef __attribute__((ext_vector_type(4))) float f32x4;

__device__ inline unsigned short f2bf(float f) {      // RNE f32 -> bf16
    unsigned u = __float_as_uint(f);
    u += 0x7fff + ((u >> 16) & 1);
    return (unsigned short)(u >> 16);
}
__device__ inline float bf2f(unsigned v) {            // low 16 bits -> f32
    return __uint_as_float(v << 16);
}

// ---------- Mega1: gemm-blocks (0..GB-1) run CONCURRENTLY with part-blocks ----
// gemm: h1b[i][c] = bf16(x[i] . W1[:,c])   (UNSCALED; dinv applied in sortb2)
// part: histogram + atomic run-reservation + scatter into padded bins.
__global__ __launch_bounds__(256) void k_mega1(const float* __restrict__ x,
                                               const float* __restrict__ W1,
                                               unsigned short* __restrict__ h1b,
                                               const int* __restrict__ src,
                                               const int* __restrict__ dst,
                                               int* __restrict__ gcnt,
                                               unsigned* __restrict__ bin,
                                               int E, int NB, int chunk,
                                               int n, int GB) {
    __shared__ uint4 bl[16 * 64];          // 16 KB union: part h/pos | W frags
    int t = threadIdx.x;

    if ((int)blockIdx.x < GB) {
        // ---- GEMM branch: 4 waves x 64 rows = 256 rows per block ----
        for (int f = t; f < 16 * 64; f += 256) {   // self-pack W1 -> LDS frags
            int kstep = f >> 6, ln = f & 63;
            int col = ln & 15, k0 = kstep * 32 + (ln >> 4) * 8;
            unsigned up[4];
#pragma unroll
            for (int i = 0; i < 4; i++) {
                float a = W1[(k0 + 2 * i) * HID + col];
                float b = W1[(k0 + 2 * i + 1) * HID + col];
                up[i] = (unsigned)f2bf(a) | ((unsigned)f2bf(b) << 16);
            }
            bl[f] = make_uint4(up[0], up[1], up[2], up[3]);
        }
        __syncthreads();

        int wid = t >> 6, lane = t & 63;
        int rows0 = blockIdx.x * 256 + wid * 64;   // this wave's 64 rows
        int arow = lane & 15, kgrp = lane >> 4;

        const float* xr[4];
#pragma unroll
        for (int rt = 0; rt < 4; rt++) {
            int r = rows0 + rt * 16 + arow;
            if (r >= n) r = n - 1;                 // clamp loads; stores guarded
            xr[rt] = x + (size_t)r * F_IN + kgrp * 8;
        }

        f32x4 acc[4];
#pragma unroll
        for (int rt = 0; rt < 4; rt++) acc[rt] = (f32x4){0.f, 0.f, 0.f, 0.f};

#pragma unroll 4
        for (int kstep = 0; kstep < 16; kstep++) {
            uint4 braw = bl[kstep * 64 + lane];
            short8 b;
            *(uint4*)&b = braw;
#pragma unroll
            for (int rt = 0; rt < 4; rt++) {
                f32x4 lo = __builtin_nontemporal_load((const f32x4*)(xr[rt] + kstep * 32));
                f32x4 hi = __builtin_nontemporal_load((const f32x4*)(xr[rt] + kstep * 32 + 4));
                __hip_bfloat162 c0 = __float22bfloat162_rn(make_float2(lo[0], lo[1]));
                __hip_bfloat162 c1 = __float22bfloat162_rn(make_float2(lo[2], lo[3]));
                __hip_bfloat162 c2 = __float22bfloat162_rn(make_float2(hi[0], hi[1]));
                __hip_bfloat162 c3 = __float22bfloat162_rn(make_float2(hi[2], hi[3]));
                uint4 araw;
                __builtin_memcpy(&araw.x, &c0, 4);
                __builtin_memcpy(&araw.y, &c1, 4);
                __builtin_memcpy(&araw.z, &c2, 4);
                __builtin_memcpy(&araw.w, &c3, 4);
                short8 a;
                *(uint4*)&a = araw;
                acc[rt] = __builtin_amdgcn_mfma_f32_16x16x32_bf16(a, b, acc[rt], 0, 0, 0);
            }
        }

        // C layout: row' = (lane>>4)*4 + r, col = lane&15
        int col = lane & 15, rbase = (lane >> 4) * 4;
#pragma unroll
        for (int rt = 0; rt < 4; rt++) {
#pragma unroll
            for (int r = 0; r < 4; r++) {
                int row = rows0 + rt * 16 + rbase + r;
                if (row < n)
                    h1b[(size_t)row * HID + col] = f2bf(acc[rt][r]);   // unscaled
            }
        }
        return;
    }

    // ---- PART branch ----
    int blk = blockIdx.x - GB;
    int* h = (int*)bl;            // 512 ints
    int* pos = h + 512;           // 512 ints (total 4 KB of the 16 KB union)
    for (int b = t; b < NB; b += 256) h[b] = 0;
    __syncthreads();
    int e0 = blk * chunk, e1 = min(E, e0 + chunk);
    int nvec = (e1 - e0) >> 2;            // int4 groups (chunk % 4 == 0)
    const int4* d4 = (const int4*)(dst + e0);
    const int4* s4 = (const int4*)(src + e0);
    for (int i = t; i < nvec; i += 256) {
        int4 d = d4[i];                   // cacheable: pass 2 hits L2
        atomicAdd(&h[d.x >> 8], 1);
        atomicAdd(&h[d.y >> 8], 1);
        atomicAdd(&h[d.z >> 8], 1);
        atomicAdd(&h[d.w >> 8], 1);
    }
    for (int e = e0 + nvec * 4 + t; e < e1; e += 256)
        atomicAdd(&h[dst[e] >> 8], 1);
    __syncthreads();
    for (int b = t; b < NB; b += 256) {
        int c = h[b];
        int rb = c ? atomicAdd(&gcnt[b], c) : 0;
        pos[b] = b * CAP + rb;
    }
    __syncthreads();
    for (int i = t; i < nvec; i += 256) { // chunk is L2-hot from pass 1
        int4 d = d4[i];
        int4 s = s4[i];
        int p;
        p = atomicAdd(&pos[d.x >> 8], 1); bin[p] = ((unsigned)s.x << 8) | (unsigned)(d.x & (TB - 1));
        p = atomicAdd(&pos[d.y >> 8], 1); bin[p] = ((unsigned)s.y << 8) | (unsigned)(d.y & (TB - 1));
        p = atomicAdd(&pos[d.z >> 8], 1); bin[p] = ((unsigned)s.z << 8) | (unsigned)(d.z & (TB - 1));
        p = atomicAdd(&pos[d.w >> 8], 1); bin[p] = ((unsigned)s.w << 8) | (unsigned)(d.w & (TB - 1));
    }
    for (int e = e0 + nvec * 4 + t; e < e1; e += 256) {
        int d = dst[e], s = src[e];
        int p = atomicAdd(&pos[d >> 8], 1);
        bin[p] = ((unsigned)s << 8) | (unsigned)(d & (TB - 1));
    }
}

// ---------- Sortb2: counting sort -> CSR + rng + dinv, AND scale h1 in place ----
__global__ __launch_bounds__(256) void k_sortb2(const unsigned* __restrict__ bin,
                                                const int* __restrict__ gcnt,
                                                int* __restrict__ csr,
                                                int2* __restrict__ rng,
                                                float* __restrict__ dinv,
                                                unsigned short* __restrict__ h1b,
                                                int N) {
    __shared__ int cnt[TB], incl[TB], pos[TB];
    int t = threadIdx.x, b = blockIdx.x;
    cnt[t] = 0;
    __syncthreads();
    int j0 = b * CAP, count = gcnt[b];
    for (int j = t; j < count; j += 256)
        atomicAdd(&cnt[bin[j0 + j] & (TB - 1)], 1);
    __syncthreads();
    incl[t] = cnt[t];
    __syncthreads();
    for (int off = 1; off < TB; off <<= 1) {
        int v = (t >= off) ? incl[t - off] : 0;
        __syncthreads();
        incl[t] += v;
        __syncthreads();
    }
    int ex = incl[t] - cnt[t];
    pos[t] = ex;
    int node = b * TB + t;
    float dv = rsqrtf((float)cnt[t] + 1.0f);      // +1 self loop
    if (node < N) {
        rng[node] = make_int2(j0 + ex, j0 + ex + cnt[t]);
        dinv[node] = dv;
        // scale this node's h1 row in place (gemm wrote it unscaled)
        uint4* p = (uint4*)(h1b + (size_t)node * HID);
        uint4 lo = p[0], hi = p[1];
        unsigned w[8] = {lo.x, lo.y, lo.z, lo.w, hi.x, hi.y, hi.z, hi.w};
#pragma unroll
        for (int i = 0; i < 8; i++) {
            float a = bf2f(w[i] & 0xffff) * dv;
            float c = bf2f(w[i] >> 16) * dv;
            w[i] = (unsigned)f2bf(a) | ((unsigned)f2bf(c) << 16);
        }
        p[0] = make_uint4(w[0], w[1], w[2], w[3]);
        p[1] = make_uint4(w[4], w[5], w[6], w[7]);
    }
    __syncthreads();
    for (int j = t; j < count; j += 256) {
        unsigned v = bin[j0 + j];
        int pp = atomicAdd(&pos[v & (TB - 1)], 1);
        csr[j0 + pp] = (int)(v >> 8);
    }
}

// ---------- Agg: grid-stride wave-per-node, 16x4; nt csr stream ----------
__global__ __launch_bounds__(256) void k_agg(const uint2* __restrict__ h1u2,
                                             const int* __restrict__ csr,
                                             const int2* __restrict__ rng,
                                             const float* __restrict__ dinv,
                                             const float* __restrict__ b1,
                                             uint2* __restrict__ zu2, int n) {
    int lane = threadIdx.x & 63;
    int wave0 = (blockIdx.x * blockDim.x + threadIdx.x) >> 6;
    int nwaves = (gridDim.x * blockDim.x) >> 6;
    int c2 = lane & 3;        // uint2 index: cols 4c2 .. 4c2+3
    int sub = lane >> 2;      // 16 subgroups -> 16 edges in flight
    float bl0 = b1[4 * c2 + 0], bl1 = b1[4 * c2 + 1];
    float bl2 = b1[4 * c2 + 2], bl3 = b1[4 * c2 + 3];
    for (int node = wave0; node < n; node += nwaves) {
        int2 r = rng[node];
        int s0 = r.x, s1 = r.y;
        uint2 us = h1u2[(size_t)node * 4 + c2];   // self loop, issued early
        float s[4] = {0.f, 0.f, 0.f, 0.f};
        int j = s0 + sub;
        int nxt = (j < s1) ? __builtin_nontemporal_load(&csr[j]) : 0;
        for (; j < s1; j += 16) {
            int cur = nxt;
            int jn = j + 16;
            if (jn < s1) nxt = __builtin_nontemporal_load(&csr[jn]);
            uint2 u = h1u2[(size_t)cur * 4 + c2];
            s[0] += bf2f(u.x & 0xffff); s[1] += bf2f(u.x >> 16);
            s[2] += bf2f(u.y & 0xffff); s[3] += bf2f(u.y >> 16);
        }
#pragma unroll
        for (int m = 4; m < 64; m <<= 1) {
            s[0] += __shfl_xor(s[0], m); s[1] += __shfl_xor(s[1], m);
            s[2] += __shfl_xor(s[2], m); s[3] += __shfl_xor(s[3], m);
        }
        s[0] += bf2f(us.x & 0xffff); s[1] += bf2f(us.x >> 16);
        s[2] += bf2f(us.y & 0xffff); s[3] += bf2f(us.y >> 16);
        float dv = dinv[node];
        float p0 = dv * s[0] + bl0;
        float p1 = dv * s[1] + bl1;
        float p2 = dv * s[2] + bl2;
        float p3 = dv * s[3] + bl3;
        if (lane < 4) {
            uint2 o;
            o.x = (unsigned)f2bf(fmaxf(p0, 0.f) * dv) | ((unsigned)f2bf(fmaxf(p1, 0.f) * dv) << 16);
            o.y = (unsigned)f2bf(fmaxf(p2, 0.f) * dv) | ((unsigned)f2bf(fmaxf(p3, 0.f) * dv) << 16);
            zu2[(size_t)node * 4 + c2] = o;
        }
    }
}

// ---------- Out: layer-2 gather (rows %20 only) + matvec + log_softmax ----------
__global__ void k_out(const unsigned short* __restrict__ zb,
                      const int* __restrict__ csr, const int2* __restrict__ rng,
                      const float* __restrict__ dinv, const float* __restrict__ W2,
                      const float* __restrict__ b2, float* __restrict__ out, int nOut) {
    int lane = threadIdx.x & 63;
    int wv = (blockIdx.x * blockDim.x + threadIdx.x) >> 6;  // one wave per out row
    if (wv >= nOut) return;
    int node = wv * OUT_STRIDE;
    int c = lane & 15, sub = lane >> 4;
    int2 r = rng[node];
    int s0 = r.x, s1 = r.y;
    float sum = 0.f;
    for (int j = s0 + sub; j < s1; j += 4)
        sum += bf2f(zb[(size_t)__builtin_nontemporal_load(&csr[j]) * HID + c]);
    sum += __shfl_xor(sum, 16);
    sum += __shfl_xor(sum, 32);
    sum += bf2f(zb[(size_t)node * HID + c]);  // self loop
    float a = dinv[node] * sum;

    int jj = lane < NCLS ? lane : 0;
    float v = 0.f;
#pragma unroll
    for (int cc = 0; cc < 16; cc++) {
        float ac = __shfl(a, cc);  // lane cc holds column cc
        v = fmaf(ac, W2[cc * NCLS + jj], v);
    }
    v += b2[jj];

    float vm = lane < NCLS ? v : -INFINITY;
    for (int off = 1; off < 64; off <<= 1) vm = fmaxf(vm, __shfl_xor(vm, off));
    float ex = lane < NCLS ? expf(v - vm) : 0.f;
    float se = ex;
    for (int off = 1; off < 64; off <<= 1) se += __shfl_xor(se, off);
    float ls = logf(se);
    if (lane < NCLS) out[(size_t)wv * NCLS + lane] = v - vm - ls;
}

// ---------------- host launcher ----------------
extern "C" void kernel_launch(void* const* d_in, const int* in_sizes, int n_in,
                              void* d_out, int out_size, void* d_ws, size_t ws_size,
                              hipStream_t stream) {
    const int E = in_sizes[0] / 2;
    const int N = in_sizes[1] / F_IN;
    const int nOut = (N + OUT_STRIDE - 1) / OUT_STRIDE;
    const int NB = (N + TB - 1) / TB;                 // 391
    const int chunk = ((E + NBA - 1) / NBA + 3) & ~3; // %4==0 for int4 loads
    const int GB = (N + 255) / 256;                   // gemm blocks (391)

    const int* src = (const int*)d_in[0];
    const int* dst = src + E;
    const float* x  = (const float*)d_in[1];
    const float* W1 = (const float*)d_in[2];
    const float* b1 = (const float*)d_in[3];
    const float* W2 = (const float*)d_in[4];
    const float* b2 = (const float*)d_in[5];
    float* out = (float*)d_out;

    uint8_t* w = (uint8_t*)d_ws;
    size_t off = 0;
    auto carve = [&](size_t bytes) {
        void* p = w + off;
        off += (bytes + 15) & ~(size_t)15;
        return p;
    };
    float*          dinv  = (float*)carve((size_t)N * 4);
    int*            gcnt  = (int*)carve((size_t)NB * 4);
    unsigned*       bin   = (unsigned*)carve((size_t)NB * CAP * 4);
    int*            csr   = (int*)carve((size_t)NB * CAP * 4);
    int2*           rng   = (int2*)carve((size_t)N * 8);
    unsigned short* h1b   = (unsigned short*)carve((size_t)N * HID * 2);
    unsigned short* zb    = (unsigned short*)carve((size_t)N * HID * 2);
    (void)ws_size; (void)n_in; (void)out_size;

    (void)hipMemsetAsync(gcnt, 0, (size_t)NB * 4, stream);
    k_mega1<<<GB + NBA, 256, 0, stream>>>(x, W1, h1b, src, dst, gcnt, bin,
                                          E, NB, chunk, N, GB);
    k_sortb2<<<NB, TB, 0, stream>>>(bin, gcnt, csr, rng, dinv, h1b, N);
    k_agg  <<<2048, 256, 0, stream>>>((const uint2*)h1b, csr, rng, dinv, b1, (uint2*)zb, N);
    k_out  <<<(nOut * 64 + 255) / 256, 256, 0, stream>>>(zb, csr, rng, dinv, W2, b2, out, nOut);
}